// Round 10
// baseline (183.593 us; speedup 1.0000x reference)
//
#include <hip/hip_runtime.h>

#define N_NODES 50000
#define N_EDGES 800000
#define NB 782                 // buckets of 64 nodes: ceil(50000/64)
#define PBLOCKS 256            // partition blocks (== count chunks)
#define CHUNK 3125             // N_EDGES / PBLOCKS (exact)
#define GEMM_BLOCKS 782        // ceil(50000/64)
#define CSR_CAP 1536           // LDS csr capacity per 64-node bucket (mean 1024 + 16 sigma)
#define HST 80                 // h_lds row stride in bf16 (160 B -> 8-bank skew)

typedef unsigned short ushort_t;
typedef __attribute__((ext_vector_type(8))) short bf16x8;   // 8 bf16 = 4 VGPR
typedef __attribute__((ext_vector_type(4))) float f32x4;    // MFMA 16x16 accum

// LESSON (round 5): LDS scatter-accumulate via __hip_atomic_fetch_add was
// catastrophically slow (350us, VALUBusy 1%). Keep the CSR + batched point-load
// gather structure below; it is the verified-good shape.
// LESSON (round 3): per-lane global weight loads + shfl GEMM fusion gets sunk
// by the compiler into a serial latency chain. Fuse GEMMs via LDS + MFMA only.
// LESSON (round 8/9): 196 blocks starves CUs (occupancy 28%); splitting buckets
// across 2 blocks duplicates the histogram and regresses. Fix: FINER RADIX --
// 64-node buckets, one whole bucket per 256-thread block, bucketstart
// precomputed by part_write so the fused kernel has no per-block scans.

__device__ __forceinline__ float bflo(unsigned int u) {
    return __uint_as_float(u << 16);
}
__device__ __forceinline__ float bfhi(unsigned int u) {
    return __uint_as_float(u & 0xffff0000u);
}
__device__ __forceinline__ ushort_t f2bf(float f) {   // round-to-nearest-even
    unsigned int x = __float_as_uint(f);
    return (ushort_t)((x + 0x7fffu + ((x >> 16) & 1u)) >> 16);
}
__device__ __forceinline__ unsigned int pack_bf(float lo, float hi) {
    return (unsigned int)f2bf(lo) | ((unsigned int)f2bf(hi) << 16);
}
// split fp32 into bf16 hi + bf16 lo (residual); hi+lo reproduces v to ~2^-17 rel
__device__ __forceinline__ void split_bf(float v, short& hi, short& lo) {
    ushort_t h = f2bf(v);
    float r = v - __uint_as_float((unsigned int)h << 16);
    hi = (short)h;
    lo = (short)f2bf(r);
}

// ---------------- Fused: layer-1 MFMA GEMM (782 blocks) + part_count (256 blocks) ----
// blocktot is TRANSPOSED: blocktot[pb * NB + bucket] (coalesced write here,
// coalesced column read in part_write).
__global__ __launch_bounds__(256)
void gemm128_and_count(const float* __restrict__ A,
                       const float* __restrict__ B1,   // [64,64] Ws1
                       const float* __restrict__ B2,   // [64,64] Wn1
                       ushort_t* __restrict__ Cself,   // [N,64] bf16
                       ushort_t* __restrict__ Cn,      // [N,64] bf16
                       const int* __restrict__ dst,
                       int* __restrict__ blocktot) {
    __shared__ int hist[NB];

    if (blockIdx.x >= GEMM_BLOCKS) {
        // ---- part_count (64-node buckets) ----
        const int pb = blockIdx.x - GEMM_BLOCKS;
        for (int i = threadIdx.x; i < NB; i += 256) hist[i] = 0;
        __syncthreads();
        const int e0 = pb * CHUNK;
        const int e1 = e0 + CHUNK;
        for (int e = e0 + (int)threadIdx.x; e < e1; e += 256)
            atomicAdd(&hist[dst[e] >> 6], 1);
        __syncthreads();
        for (int i = threadIdx.x; i < NB; i += 256)
            blocktot[pb * NB + i] = hist[i];
        return;
    }

    const int l  = threadIdx.x & 63;
    const int w  = threadIdx.x >> 6;     // wave 0..3
    const int lr = l & 15;
    const int lk = (l >> 4) << 3;        // 0,8,16,24

    // ---- B fragments in registers (hi/lo split), cols 32w .. 32w+31 ----
    bf16x8 bhi[2][2], blo[2][2];         // [nt][ks]
#pragma unroll
    for (int nt = 0; nt < 2; ++nt) {
        const int n = w * 32 + nt * 16 + lr;             // 0..127
        const float* Bp = (n < 64) ? (B1 + n) : (B2 + (n - 64));
#pragma unroll
        for (int ks = 0; ks < 2; ++ks) {
#pragma unroll
            for (int j = 0; j < 8; ++j) {
                float bv = Bp[(size_t)(ks * 32 + lk + j) * 64];
                short h, lo;
                split_bf(bv, h, lo);
                bhi[nt][ks][j] = h;
                blo[nt][ks][j] = lo;
            }
        }
    }

    const int m0 = blockIdx.x * 64;
    f32x4 acc[4][2];
#pragma unroll
    for (int mt = 0; mt < 4; ++mt)
#pragma unroll
        for (int nt = 0; nt < 2; ++nt) {
            f32x4 z = {0.f, 0.f, 0.f, 0.f};
            acc[mt][nt] = z;
        }

#pragma unroll
    for (int mt = 0; mt < 4; ++mt) {
        const int m = m0 + mt * 16 + lr;
        const bool valid = (m < N_NODES);
        const float* Ap = A + (size_t)m * 64 + lk;
#pragma unroll
        for (int ks = 0; ks < 2; ++ks) {
            float4 f0, f1;
            if (valid) {
                f0 = *(const float4*)(Ap + ks * 32);
                f1 = *(const float4*)(Ap + ks * 32 + 4);
            } else {
                f0 = make_float4(0.f, 0.f, 0.f, 0.f);
                f1 = f0;
            }
            const float fv[8] = {f0.x, f0.y, f0.z, f0.w, f1.x, f1.y, f1.z, f1.w};
            bf16x8 ahi, alo;
#pragma unroll
            for (int j = 0; j < 8; ++j) {
                short h, lo;
                split_bf(fv[j], h, lo);
                ahi[j] = h;
                alo[j] = lo;
            }
#pragma unroll
            for (int nt = 0; nt < 2; ++nt) {
                acc[mt][nt] = __builtin_amdgcn_mfma_f32_16x16x32_bf16(
                    ahi, bhi[nt][ks], acc[mt][nt], 0, 0, 0);
                acc[mt][nt] = __builtin_amdgcn_mfma_f32_16x16x32_bf16(
                    alo, bhi[nt][ks], acc[mt][nt], 0, 0, 0);
                acc[mt][nt] = __builtin_amdgcn_mfma_f32_16x16x32_bf16(
                    ahi, blo[nt][ks], acc[mt][nt], 0, 0, 0);
            }
        }
    }

    // ---- store: D lane col = l&15 (+tiles), rows (l>>4)*4 + r ----
#pragma unroll
    for (int mt = 0; mt < 4; ++mt) {
        const int mbase = m0 + mt * 16 + ((l >> 4) << 2);
#pragma unroll
        for (int nt = 0; nt < 2; ++nt) {
            const int n = w * 32 + nt * 16 + lr;
            ushort_t* T = (n < 64) ? (Cself + n) : (Cn + (n - 64));
#pragma unroll
            for (int r = 0; r < 4; ++r) {
                const int m = mbase + r;
                if (m < N_NODES) T[(size_t)m * 64] = f2bf(acc[mt][nt][r]);
            }
        }
    }
}

// ---------------- part_write: radix partition to 64-node buckets ----------------
// 1024 threads; thread t scans blocktot column t (transposed layout -> coalesced)
// to get row total + partial at pb; 1024-scan gives bucket starts; pb==0 emits
// bucketstart[] for the fused gather kernel (no per-block scans downstream).
__global__ __launch_bounds__(1024)
void part_write(const int* __restrict__ src, const int* __restrict__ dst,
                const int* __restrict__ blocktot, unsigned int* __restrict__ brec,
                int* __restrict__ bucketstart) {
    __shared__ int psum[1024];
    __shared__ int cur[NB];
    const int pb = blockIdx.x;           // 0..PBLOCKS-1
    const int t  = threadIdx.x;

    int rsum = 0, mypart = 0;
    if (t < NB) {
#pragma unroll 8
        for (int j = 0; j < PBLOCKS; ++j) {
            if (j == pb) mypart = rsum;
            rsum += blocktot[j * NB + t];
        }
    }
    psum[t] = rsum;
    __syncthreads();
    for (int off = 1; off < 1024; off <<= 1) {
        int add = (t >= off) ? psum[t - off] : 0;
        __syncthreads();
        psum[t] += add;
        __syncthreads();
    }
    if (t < NB) {
        const int rowpre = psum[t] - rsum;      // bucket-t start in brec
        cur[t] = rowpre + mypart;               // + this partition's offset
        if (pb == 0) bucketstart[t] = rowpre;
    }
    if (pb == 0 && t == 0) bucketstart[NB] = N_EDGES;
    __syncthreads();

    const int e0 = pb * CHUNK;
    const int e1 = e0 + CHUNK;
    for (int e = e0 + t; e < e1; e += 1024) {
        int d = dst[e];
        int s = src[e];
        int pos = atomicAdd(&cur[d >> 6], 1);
        brec[pos] = ((unsigned int)(d & 63) << 16) | (unsigned int)s;
    }
}

// ---------------- FUSED: bucket CSR build + layer-1 gather + layer-2 MFMA GEMM ----
// One 256-thread block per 64-node bucket (grid 782 -> all CUs, ~3 blocks/CU
// co-resident at 17 KB LDS / 4 waves). No per-block control scans: [w0,w1)
// comes from bucketstart. Gather inner shape = verified round-4; layer-2 GEMM
// = verified gemm_cat64 MFMA pattern on LDS-staged h.
__global__ __launch_bounds__(256)
void csr_gather1_g2(const unsigned int* __restrict__ brec,
                    const int* __restrict__ bucketstart,
                    int* __restrict__ csr_src, int* __restrict__ row_ptr,
                    const ushort_t* __restrict__ Tself,
                    const ushort_t* __restrict__ Tn,
                    const float* __restrict__ bias,        // b1
                    const float* __restrict__ Ws2,         // [64,32]
                    const float* __restrict__ Wn2,         // [64,32]
                    ushort_t* __restrict__ Tself2,         // [N,32] bf16
                    ushort_t* __restrict__ Tn2) {          // [N,32] bf16
    __shared__ int cnt[64];
    __shared__ int rs[64];
    __shared__ int cur[64];
    __shared__ int csr_lds[CSR_CAP];        // 6 KB
    __shared__ ushort_t h_lds[64 * HST];    // 10 KB

    const int b = blockIdx.x;
    const int node0 = b * 64;
    const int t = threadIdx.x;
    const int w0 = bucketstart[b];
    const int w1 = bucketstart[b + 1];

    if (t < 64) cnt[t] = 0;
    __syncthreads();

    // ---- histogram of own ~1024 records ----
    for (int i = w0 + t; i < w1; i += 256)
        atomicAdd(&cnt[brec[i] >> 16], 1);
    __syncthreads();

    // ---- 64-wide scan -> rs (exclusive); row_ptr global ----
    if (t < 64) cur[t] = cnt[t];
    __syncthreads();
    for (int off = 1; off < 64; off <<= 1) {
        int add = (t < 64 && t >= off) ? cur[t - off] : 0;
        __syncthreads();
        if (t < 64) cur[t] += add;
        __syncthreads();
    }
    if (t < 64) {
        const int excl = cur[t] - cnt[t];
        rs[t] = excl;
        const int node = node0 + t;
        if (node <= N_NODES) row_ptr[node] = w0 + excl;
        cur[t] = excl;                      // scatter cursor (bucket-local)
    }
    __syncthreads();

    // ---- scatter: LDS csr + global csr_src (for gather2) ----
    for (int i = w0 + t; i < w1; i += 256) {
        const unsigned int r = brec[i];
        const int pos = atomicAdd(&cur[r >> 16], 1);
        const int s = (int)(r & 0xffffu);
        csr_src[w0 + pos] = s;
        if (pos < CSR_CAP) csr_lds[pos] = s;
    }
    __syncthreads();

    // ---- gather phase: 4 waves x 8 iters x 2 nodes = 64 nodes ----
    const int wv   = t >> 6;           // wave 0..3
    const int lane = t & 63;
    const int lh   = lane >> 5;        // node slot within wave
    const int hl   = lane & 31;
    const int r = hl >> 3;             // row-group 0..3
    const int c = hl & 7;              // cols c*8 .. c*8+7

#define ACC8(u)                                           \
    a[0] += bflo(u.x); a[1] += bfhi(u.x);                 \
    a[2] += bflo(u.y); a[3] += bfhi(u.y);                 \
    a[4] += bflo(u.z); a[5] += bfhi(u.z);                 \
    a[6] += bflo(u.w); a[7] += bfhi(u.w);

    for (int it = 0; it < 8; ++it) {
        const int dloc = (((wv + (it << 2)) << 1) + lh);  // 0..63
        const int v = node0 + dloc;
        if (v >= N_NODES) continue;
        const int sl = rs[dloc];
        const int cn = cnt[dloc];

        float a[8];
#pragma unroll
        for (int i = 0; i < 8; ++i) a[i] = 0.f;

        const int nfast = (cn < 32) ? cn : 32;
        int  sidx[8];
        bool act[8];
#pragma unroll
        for (int j = 0; j < 8; ++j) {
            const int tt = r + (j << 2);
            act[j] = (tt < nfast);
            sidx[j] = 0;
            if (act[j]) {
                const int ad = sl + tt;
                sidx[j] = (ad < CSR_CAP) ? csr_lds[ad] : csr_src[w0 + ad];
            }
        }
        uint4 u[8];
#pragma unroll
        for (int j = 0; j < 8; ++j) {
            u[j] = make_uint4(0u, 0u, 0u, 0u);
            if (act[j]) u[j] = *(const uint4*)&Tn[(size_t)sidx[j] * 64 + c * 8];
        }
#pragma unroll
        for (int j = 0; j < 8; ++j) { ACC8(u[j]) }

        // rare tail: cn > 32
        for (int tt = 32 + r; tt < cn; tt += 4) {
            const int ad = sl + tt;
            const int s = (ad < CSR_CAP) ? csr_lds[ad] : csr_src[w0 + ad];
            const uint4 uu = *(const uint4*)&Tn[(size_t)s * 64 + c * 8];
            ACC8(uu)
        }

        // butterfly within the 32-lane half
#pragma unroll
        for (int off = 8; off < 32; off <<= 1) {
#pragma unroll
            for (int i = 0; i < 8; ++i) a[i] += __shfl_xor(a[i], off);
        }

        if (r == 0) {
            const float inv = 1.0f / (float)max(cn, 1);
            uint4 su = *(const uint4*)&Tself[(size_t)v * 64 + c * 8];
            float4 bA = *(const float4*)&bias[c * 8];
            float4 bB = *(const float4*)&bias[c * 8 + 4];
            float o[8];
            o[0] = bflo(su.x) + a[0] * inv + bA.x;
            o[1] = bfhi(su.x) + a[1] * inv + bA.y;
            o[2] = bflo(su.y) + a[2] * inv + bA.z;
            o[3] = bfhi(su.y) + a[3] * inv + bA.w;
            o[4] = bflo(su.z) + a[4] * inv + bB.x;
            o[5] = bfhi(su.z) + a[5] * inv + bB.y;
            o[6] = bflo(su.w) + a[6] * inv + bB.z;
            o[7] = bfhi(su.w) + a[7] * inv + bB.w;
#pragma unroll
            for (int i = 0; i < 8; ++i) o[i] = fmaxf(o[i], 0.f);
            uint4 p;
            p.x = pack_bf(o[0], o[1]); p.y = pack_bf(o[2], o[3]);
            p.z = pack_bf(o[4], o[5]); p.w = pack_bf(o[6], o[7]);
            *(uint4*)&h_lds[dloc * HST + c * 8] = p;     // h row -> LDS (not global)
        }
    }
#undef ACC8
    __syncthreads();

    // ---- layer-2 MFMA GEMM on LDS h: wave wv owns rows wv*16..wv*16+15 ----
    const int lr  = lane & 15;
    const int lk2 = (lane >> 4) << 3;      // 0,8,16,24

    // B fragments (hi/lo split): n = nt*16 + lr, k = ks*32 + lk2 + j
    bf16x8 bhi[4][2], blo[4][2];
#pragma unroll
    for (int nt = 0; nt < 4; ++nt) {
        const int n = nt * 16 + lr;        // 0..63
        const float* Bp = (n < 32) ? (Ws2 + n) : (Wn2 + (n - 32));
#pragma unroll
        for (int ks = 0; ks < 2; ++ks) {
#pragma unroll
            for (int j = 0; j < 8; ++j) {
                float bv = Bp[(size_t)(ks * 32 + lk2 + j) * 32];
                short h, lo;
                split_bf(bv, h, lo);
                bhi[nt][ks][j] = h;
                blo[nt][ks][j] = lo;
            }
        }
    }

    f32x4 acc2[4];
#pragma unroll
    for (int nt = 0; nt < 4; ++nt) {
        f32x4 z = {0.f, 0.f, 0.f, 0.f};
        acc2[nt] = z;
    }
#pragma unroll
    for (int ks = 0; ks < 2; ++ks) {
        const bf16x8 a = *(const bf16x8*)&h_lds[(wv * 16 + lr) * HST + ks * 32 + lk2];
#pragma unroll
        for (int nt = 0; nt < 4; ++nt) {
            acc2[nt] = __builtin_amdgcn_mfma_f32_16x16x32_bf16(a, bhi[nt][ks], acc2[nt], 0, 0, 0);
            acc2[nt] = __builtin_amdgcn_mfma_f32_16x16x32_bf16(a, blo[nt][ks], acc2[nt], 0, 0, 0);
        }
    }

    // store: col n = nt*16+lr; rows node0 + wv*16 + (lane>>4)*4 + rr
    const int mbase = node0 + wv * 16 + ((lane >> 4) << 2);
#pragma unroll
    for (int nt = 0; nt < 4; ++nt) {
        const int n = nt * 16 + lr;
        ushort_t* T = (n < 32) ? (Tself2 + n) : (Tn2 + (n - 32));
#pragma unroll
        for (int rr = 0; rr < 4; ++rr) {
            const int m = mbase + rr;
            if (m < N_NODES) T[(size_t)m * 32] = f2bf(acc2[nt][rr]);
        }
    }
}

// ---------------- Layer-2 gather (F=32): 4 nodes/wave, 16 lanes each ----------------
__global__ __launch_bounds__(256)
void gather2(const ushort_t* __restrict__ Tself,
             const ushort_t* __restrict__ Tn,
             const int* __restrict__ row_ptr,
             const int* __restrict__ csr_src, const float* __restrict__ bias,
             float* __restrict__ out) {
    constexpr int F = 32;
    constexpr int LPR = 4;           // lanes per row (4 x 16B = 64B row)
    constexpr int G = 4;             // row-groups per node (16/LPR)
    constexpr int MAXJ = 8;          // fast-path rows per group (covers cnt<=32)
    const int lane = threadIdx.x & 63;
    const int q  = lane >> 4;        // node slot within wave (0..3)
    const int hl = lane & 15;
    const int r = hl >> 2;           // row-group 0..3
    const int c = hl & 3;            // cols c*8 .. c*8+7
    const int v = (((int)blockIdx.x * (int)blockDim.x + (int)threadIdx.x) >> 6) * 4 + q;
    if (v >= N_NODES) return;
    const int start = row_ptr[v];
    const int cnt   = row_ptr[v + 1] - start;

    float a[8];
#pragma unroll
    for (int i = 0; i < 8; ++i) a[i] = 0.f;

#define ACC8(u)                                           \
    a[0] += bflo(u.x); a[1] += bfhi(u.x);                 \
    a[2] += bflo(u.y); a[3] += bfhi(u.y);                 \
    a[4] += bflo(u.z); a[5] += bfhi(u.z);                 \
    a[6] += bflo(u.w); a[7] += bfhi(u.w);

    // ---- two coalesced index loads per lane: covers indices 0..31 ----
    int idx0 = 0, idx1 = 0;
    if (hl < cnt)      idx0 = csr_src[start + hl];
    if (16 + hl < cnt) idx1 = csr_src[start + 16 + hl];

    const int nfast = (cnt < 32) ? cnt : 32;
    int  sidx[MAXJ];
    bool act[MAXJ];
#pragma unroll
    for (int j = 0; j < MAXJ; ++j) {
        const int t = r + j * G;                 // j<4 -> t<16 ; j>=4 -> t>=16
        act[j] = (t < nfast);
        sidx[j] = (j < 4) ? __shfl(idx0, q * 16 + t)
                          : __shfl(idx1, q * 16 + (t - 16));
    }
    uint4 u[MAXJ];
#pragma unroll
    for (int j = 0; j < MAXJ; ++j) {
        u[j] = make_uint4(0u, 0u, 0u, 0u);
        if (act[j]) u[j] = *(const uint4*)&Tn[(size_t)sidx[j] * F + c * 8];
    }
#pragma unroll
    for (int j = 0; j < MAXJ; ++j) { ACC8(u[j]) }

    // ---- rare tail: cnt > 32 ----
    for (int t = 32 + r; t < cnt; t += G) {
        const int s = csr_src[start + t];
        uint4 uu = *(const uint4*)&Tn[(size_t)s * F + c * 8];
        ACC8(uu)
    }
#undef ACC8

    // ---- reduce across 4 row-groups (within the 16-lane quarter) ----
#pragma unroll
    for (int off = LPR; off < 16; off <<= 1) {
#pragma unroll
        for (int i = 0; i < 8; ++i) a[i] += __shfl_xor(a[i], off);
    }

    if (r == 0) {
        const float inv = 1.0f / (float)max(cnt, 1);
        uint4 su = *(const uint4*)&Tself[(size_t)v * F + c * 8];
        float4 bA = *(const float4*)&bias[c * 8];
        float4 bB = *(const float4*)&bias[c * 8 + 4];
        float o[8];
        o[0] = bflo(su.x) + a[0] * inv + bA.x;
        o[1] = bfhi(su.x) + a[1] * inv + bA.y;
        o[2] = bflo(su.y) + a[2] * inv + bA.z;
        o[3] = bfhi(su.y) + a[3] * inv + bA.w;
        o[4] = bflo(su.z) + a[4] * inv + bB.x;
        o[5] = bfhi(su.z) + a[5] * inv + bB.y;
        o[6] = bflo(su.w) + a[6] * inv + bB.z;
        o[7] = bfhi(su.w) + a[7] * inv + bB.w;
        *(float4*)&out[(size_t)v * F + c * 8]     = make_float4(o[0], o[1], o[2], o[3]);
        *(float4*)&out[(size_t)v * F + c * 8 + 4] = make_float4(o[4], o[5], o[6], o[7]);
    }
}

extern "C" void kernel_launch(void* const* d_in, const int* in_sizes, int n_in,
                              void* d_out, int out_size, void* d_ws, size_t ws_size,
                              hipStream_t stream) {
    const float* features = (const float*)d_in[0];
    const float* W_self1  = (const float*)d_in[1];
    const float* W_neigh1 = (const float*)d_in[2];
    const float* b1       = (const float*)d_in[3];
    const float* W_self2  = (const float*)d_in[4];
    const float* W_neigh2 = (const float*)d_in[5];
    const float* b2       = (const float*)d_in[6];
    const int*   src      = (const int*)d_in[7];
    const int*   dst      = (const int*)d_in[8];

    // Workspace:
    //   Tself1 : N*64 bf16 (6.4 MB)
    //   Tn1    : N*64 bf16 (6.4 MB)
    //   T2     : N*64 bf16 (6.4 MB) = Tself2 (N*32) | Tn2 (N*32)
    //   row_ptr: N+1; csr_src: E; brec: E; blocktot: PBLOCKS*NB; bucketstart: NB+1
    ushort_t* Tself1 = (ushort_t*)d_ws;
    ushort_t* Tn1    = Tself1 + (size_t)N_NODES * 64;
    ushort_t* T2     = Tn1 + (size_t)N_NODES * 64;
    int* row_ptr     = (int*)(T2 + (size_t)N_NODES * 64);
    int* csr_src     = row_ptr + (N_NODES + 1);
    unsigned int* brec = (unsigned int*)(csr_src + N_EDGES);
    int* blocktot    = (int*)(brec + N_EDGES);
    int* bucketstart = blocktot + PBLOCKS * NB;

    ushort_t* Tself2 = T2;
    ushort_t* Tn2    = T2 + (size_t)N_NODES * 32;

    // ---- 1: layer-1 MFMA GEMM overlapped with CSR count ----
    gemm128_and_count<<<GEMM_BLOCKS + PBLOCKS, 256, 0, stream>>>(
        features, W_self1, W_neigh1, Tself1, Tn1, dst, blocktot);
    // ---- 2: radix partition write (emits bucketstart) ----
    part_write<<<PBLOCKS, 1024, 0, stream>>>(src, dst, blocktot, brec, bucketstart);
    // ---- 3: FUSED CSR build + layer-1 gather + layer-2 GEMM (782 blocks) ----
    csr_gather1_g2<<<NB, 256, 0, stream>>>(
        brec, bucketstart, csr_src, row_ptr, Tself1, Tn1, b1,
        W_self2, W_neigh2, Tself2, Tn2);
    // ---- 4: layer-2 gather + epilogue -> out (fp32) ----
    gather2<<<(N_NODES + 15) / 16, 256, 0, stream>>>(
        Tself2, Tn2, row_ptr, csr_src, b2, (float*)d_out);
}

// Round 11
// 157.708 us; speedup vs baseline: 1.1641x; 1.1641x over previous
//
#include <hip/hip_runtime.h>

#define N_NODES 50000
#define N_EDGES 800000
#define NB 250                 // buckets of 200 nodes: 250*200 == 50000 exactly
#define BW 200                 // bucket width (nodes)
#define PBLOCKS 256            // partition blocks (== count chunks)
#define CHUNK 3125             // N_EDGES / PBLOCKS (exact)
#define GEMM_BLOCKS 782        // ceil(50000/64)
#define CSR_CAP 4096           // LDS csr capacity per bucket (mean 3200 + 15 sigma)
#define HST 80                 // h_lds row stride in bf16 (160 B -> 8-bank skew)

typedef unsigned short ushort_t;
typedef __attribute__((ext_vector_type(8))) short bf16x8;   // 8 bf16 = 4 VGPR
typedef __attribute__((ext_vector_type(4))) float f32x4;    // MFMA 16x16 accum

// LESSON (round 5): LDS scatter-accumulate via __hip_atomic_fetch_add was
// catastrophically slow (350us, VALUBusy 1%). Keep the CSR + batched point-load
// gather structure below; it is the verified-good shape.
// LESSON (round 3): per-lane global weight loads + shfl GEMM fusion gets sunk
// by the compiler into a serial latency chain. Fuse GEMMs via LDS + MFMA only.
// LESSON (rounds 8-10): the fused kernel runs best as ONE 16-wave block per CU
// (round-8 shape). Splitting buckets (r9) duplicates histograms; small blocks
// (r10) hit register-pressure wave caps. The fix for 196<256 CU idling is
// 250 buckets of 200 nodes: same block shape, full CU coverage, no tail.

__device__ __forceinline__ float bflo(unsigned int u) {
    return __uint_as_float(u << 16);
}
__device__ __forceinline__ float bfhi(unsigned int u) {
    return __uint_as_float(u & 0xffff0000u);
}
__device__ __forceinline__ ushort_t f2bf(float f) {   // round-to-nearest-even
    unsigned int x = __float_as_uint(f);
    return (ushort_t)((x + 0x7fffu + ((x >> 16) & 1u)) >> 16);
}
__device__ __forceinline__ unsigned int pack_bf(float lo, float hi) {
    return (unsigned int)f2bf(lo) | ((unsigned int)f2bf(hi) << 16);
}
// split fp32 into bf16 hi + bf16 lo (residual); hi+lo reproduces v to ~2^-17 rel
__device__ __forceinline__ void split_bf(float v, short& hi, short& lo) {
    ushort_t h = f2bf(v);
    float r = v - __uint_as_float((unsigned int)h << 16);
    hi = (short)h;
    lo = (short)f2bf(r);
}
// bucket(d) = d / 200 for d < 50000, via d/200 = (d>>3)/25 and magic-div by 25:
// m = ceil(2^17/25) = 5243, err = 3; 3 * 6249 < 2^17 -> exact (Granlund).
__device__ __forceinline__ int bucket_of(int d) {
    return ((d >> 3) * 5243) >> 17;
}

// ---------------- Fused: layer-1 MFMA GEMM (782 blocks) + part_count (256 blocks) ----
__global__ __launch_bounds__(256)
void gemm128_and_count(const float* __restrict__ A,
                       const float* __restrict__ B1,   // [64,64] Ws1
                       const float* __restrict__ B2,   // [64,64] Wn1
                       ushort_t* __restrict__ Cself,   // [N,64] bf16
                       ushort_t* __restrict__ Cn,      // [N,64] bf16
                       const int* __restrict__ dst,
                       int* __restrict__ blocktot) {
    __shared__ int hist[NB];

    if (blockIdx.x >= GEMM_BLOCKS) {
        // ---- part_count (200-node buckets) ----
        const int pb = blockIdx.x - GEMM_BLOCKS;
        for (int i = threadIdx.x; i < NB; i += 256) hist[i] = 0;
        __syncthreads();
        const int e0 = pb * CHUNK;
        const int e1 = e0 + CHUNK;
        for (int e = e0 + (int)threadIdx.x; e < e1; e += 256)
            atomicAdd(&hist[bucket_of(dst[e])], 1);
        __syncthreads();
        for (int i = threadIdx.x; i < NB; i += 256)
            blocktot[i * PBLOCKS + pb] = hist[i];
        return;
    }

    const int l  = threadIdx.x & 63;
    const int w  = threadIdx.x >> 6;     // wave 0..3
    const int lr = l & 15;
    const int lk = (l >> 4) << 3;        // 0,8,16,24

    // ---- B fragments in registers (hi/lo split), cols 32w .. 32w+31 ----
    bf16x8 bhi[2][2], blo[2][2];         // [nt][ks]
#pragma unroll
    for (int nt = 0; nt < 2; ++nt) {
        const int n = w * 32 + nt * 16 + lr;             // 0..127
        const float* Bp = (n < 64) ? (B1 + n) : (B2 + (n - 64));
#pragma unroll
        for (int ks = 0; ks < 2; ++ks) {
#pragma unroll
            for (int j = 0; j < 8; ++j) {
                float bv = Bp[(size_t)(ks * 32 + lk + j) * 64];
                short h, lo;
                split_bf(bv, h, lo);
                bhi[nt][ks][j] = h;
                blo[nt][ks][j] = lo;
            }
        }
    }

    const int m0 = blockIdx.x * 64;
    f32x4 acc[4][2];
#pragma unroll
    for (int mt = 0; mt < 4; ++mt)
#pragma unroll
        for (int nt = 0; nt < 2; ++nt) {
            f32x4 z = {0.f, 0.f, 0.f, 0.f};
            acc[mt][nt] = z;
        }

#pragma unroll
    for (int mt = 0; mt < 4; ++mt) {
        const int m = m0 + mt * 16 + lr;
        const bool valid = (m < N_NODES);
        const float* Ap = A + (size_t)m * 64 + lk;
#pragma unroll
        for (int ks = 0; ks < 2; ++ks) {
            float4 f0, f1;
            if (valid) {
                f0 = *(const float4*)(Ap + ks * 32);
                f1 = *(const float4*)(Ap + ks * 32 + 4);
            } else {
                f0 = make_float4(0.f, 0.f, 0.f, 0.f);
                f1 = f0;
            }
            const float fv[8] = {f0.x, f0.y, f0.z, f0.w, f1.x, f1.y, f1.z, f1.w};
            bf16x8 ahi, alo;
#pragma unroll
            for (int j = 0; j < 8; ++j) {
                short h, lo;
                split_bf(fv[j], h, lo);
                ahi[j] = h;
                alo[j] = lo;
            }
#pragma unroll
            for (int nt = 0; nt < 2; ++nt) {
                acc[mt][nt] = __builtin_amdgcn_mfma_f32_16x16x32_bf16(
                    ahi, bhi[nt][ks], acc[mt][nt], 0, 0, 0);
                acc[mt][nt] = __builtin_amdgcn_mfma_f32_16x16x32_bf16(
                    alo, bhi[nt][ks], acc[mt][nt], 0, 0, 0);
                acc[mt][nt] = __builtin_amdgcn_mfma_f32_16x16x32_bf16(
                    ahi, blo[nt][ks], acc[mt][nt], 0, 0, 0);
            }
        }
    }

    // ---- store: D lane col = l&15 (+tiles), rows (l>>4)*4 + r ----
#pragma unroll
    for (int mt = 0; mt < 4; ++mt) {
        const int mbase = m0 + mt * 16 + ((l >> 4) << 2);
#pragma unroll
        for (int nt = 0; nt < 2; ++nt) {
            const int n = w * 32 + nt * 16 + lr;
            ushort_t* T = (n < 64) ? (Cself + n) : (Cn + (n - 64));
#pragma unroll
            for (int r = 0; r < 4; ++r) {
                const int m = mbase + r;
                if (m < N_NODES) T[(size_t)m * 64] = f2bf(acc[mt][nt][r]);
            }
        }
    }
}

// ---------------- part_write with self-computed prefixes ----------------
__global__ __launch_bounds__(256)
void part_write(const int* __restrict__ src, const int* __restrict__ dst,
                const int* __restrict__ blocktot, unsigned int* __restrict__ brec) {
    __shared__ int ssum[256];
    __shared__ int cur[NB];
    const int pb = blockIdx.x;           // 0..PBLOCKS-1
    const int t  = threadIdx.x;

    int rsum = 0, mypart = 0;
    if (t < NB) {
        const int* rp = blocktot + t * PBLOCKS;
#pragma unroll 8
        for (int j = 0; j < PBLOCKS; ++j) {
            if (j == pb) mypart = rsum;
            rsum += rp[j];
        }
    }
    ssum[t] = (t < NB) ? rsum : 0;
    __syncthreads();
    for (int off = 1; off < 256; off <<= 1) {
        int add = (t >= off) ? ssum[t - off] : 0;
        __syncthreads();
        ssum[t] += add;
        __syncthreads();
    }
    if (t < NB) cur[t] = (ssum[t] - rsum) + mypart;   // rowpre(t) + colpart(t)
    __syncthreads();

    const int e0 = pb * CHUNK;
    const int e1 = e0 + CHUNK;
    for (int e = e0 + t; e < e1; e += 256) {
        int d = dst[e];
        int s = src[e];
        int b = bucket_of(d);
        int pos = atomicAdd(&cur[b], 1);
        brec[pos] = ((unsigned int)(d - b * BW) << 16) | (unsigned int)s;
    }
}

// ---------------- FUSED: bucket CSR build + layer-1 gather + layer-2 MFMA GEMM ----
// One 1024-thread (16-wave) block per 200-node bucket. 250 blocks -> every CU
// busy, zero tail. Phases: bucket scan -> histogram -> node scan -> scatter ->
// gather (verified round-4 inner shape) -> layer-2 MFMA GEMM on LDS h.
__global__ __launch_bounds__(1024)
void csr_gather1_g2(const int* __restrict__ blocktot,
                    const unsigned int* __restrict__ brec,
                    int* __restrict__ csr_src, int* __restrict__ row_ptr,
                    const ushort_t* __restrict__ Tself,
                    const ushort_t* __restrict__ Tn,
                    const float* __restrict__ bias,        // b1
                    const float* __restrict__ Ws2,         // [64,32]
                    const float* __restrict__ Wn2,         // [64,32]
                    ushort_t* __restrict__ Tself2,         // [N,32] bf16
                    ushort_t* __restrict__ Tn2) {          // [N,32] bf16
    __shared__ int ssum[256];
    __shared__ int cnt[256];
    __shared__ int rs[256];
    __shared__ int cur[256];
    __shared__ int csr_lds[CSR_CAP];        // 16 KB
    __shared__ ushort_t h_lds[256 * HST];   // 40 KB (rows 200..255 scratch)

    const int b = blockIdx.x;
    const int node0 = b * BW;
    const int t = threadIdx.x;

    // ---- bucket [w0,w1) from blocktot row sums + 256-scan ----
    if (t < 256) {
        int rsum = 0;
        if (t < NB) {
            const int* rp = blocktot + t * PBLOCKS;
#pragma unroll 8
            for (int j = 0; j < PBLOCKS; ++j) rsum += rp[j];
        }
        ssum[t] = rsum;
        cnt[t] = 0;
    }
    __syncthreads();
    for (int off = 1; off < 256; off <<= 1) {
        int add = (t < 256 && t >= off) ? ssum[t - off] : 0;
        __syncthreads();
        if (t < 256) ssum[t] += add;
        __syncthreads();
    }
    const int w0 = (b == 0) ? 0 : ssum[b - 1];
    const int w1 = ssum[b];
    __syncthreads();

    // ---- histogram of own ~3200 records ----
    for (int i = w0 + t; i < w1; i += 1024)
        atomicAdd(&cnt[brec[i] >> 16], 1);
    __syncthreads();

    // ---- scan cnt -> rs (exclusive, bucket-local); row_ptr global ----
    if (t < 256) cur[t] = cnt[t];
    __syncthreads();
    for (int off = 1; off < 256; off <<= 1) {
        int add = (t < 256 && t >= off) ? cur[t - off] : 0;
        __syncthreads();
        if (t < 256) cur[t] += add;
        __syncthreads();
    }
    if (t < 256) {
        const int excl = cur[t] - cnt[t];
        rs[t] = excl;
        if (t < BW) row_ptr[node0 + t] = w0 + excl;
        cur[t] = excl;                      // scatter cursor (bucket-local)
    }
    if (b == NB - 1 && t == 0) row_ptr[N_NODES] = N_EDGES;
    __syncthreads();

    // ---- scatter: LDS csr + global csr_src (for gather2) ----
    for (int i = w0 + t; i < w1; i += 1024) {
        const unsigned int r = brec[i];
        const int pos = atomicAdd(&cur[r >> 16], 1);
        const int s = (int)(r & 0xffffu);
        csr_src[w0 + pos] = s;
        if (pos < CSR_CAP) csr_lds[pos] = s;
    }
    __syncthreads();

    // ---- gather phase: 16 waves x 7 iters x 2 nodes -> 200 nodes ----
    const int wv   = t >> 6;           // wave 0..15
    const int lane = t & 63;
    const int half = lane >> 5;        // node slot within wave
    const int hl   = lane & 31;
    const int r = hl >> 3;             // row-group 0..3
    const int c = hl & 7;              // cols c*8 .. c*8+7

#define ACC8(u)                                           \
    a[0] += bflo(u.x); a[1] += bfhi(u.x);                 \
    a[2] += bflo(u.y); a[3] += bfhi(u.y);                 \
    a[4] += bflo(u.z); a[5] += bfhi(u.z);                 \
    a[6] += bflo(u.w); a[7] += bfhi(u.w);

    for (int it = 0; it < 7; ++it) {
        const int pair = wv + (it << 4);        // 0..111
        if (pair >= 100) continue;              // 100 pairs = 200 nodes
        const int dloc = (pair << 1) + half;    // 0..199
        const int v = node0 + dloc;             // always < N_NODES (250*200 exact)
        const int sl = rs[dloc];
        const int cn = cnt[dloc];

        float a[8];
#pragma unroll
        for (int i = 0; i < 8; ++i) a[i] = 0.f;

        const int nfast = (cn < 32) ? cn : 32;
        int  sidx[8];
        bool act[8];
#pragma unroll
        for (int j = 0; j < 8; ++j) {
            const int tt = r + (j << 2);
            act[j] = (tt < nfast);
            sidx[j] = 0;
            if (act[j]) {
                const int ad = sl + tt;
                sidx[j] = (ad < CSR_CAP) ? csr_lds[ad] : csr_src[w0 + ad];
            }
        }
        uint4 u[8];
#pragma unroll
        for (int j = 0; j < 8; ++j) {
            u[j] = make_uint4(0u, 0u, 0u, 0u);
            if (act[j]) u[j] = *(const uint4*)&Tn[(size_t)sidx[j] * 64 + c * 8];
        }
#pragma unroll
        for (int j = 0; j < 8; ++j) { ACC8(u[j]) }

        // rare tail: cn > 32
        for (int tt = 32 + r; tt < cn; tt += 4) {
            const int ad = sl + tt;
            const int s = (ad < CSR_CAP) ? csr_lds[ad] : csr_src[w0 + ad];
            const uint4 uu = *(const uint4*)&Tn[(size_t)s * 64 + c * 8];
            ACC8(uu)
        }

        // butterfly within the 32-lane half
#pragma unroll
        for (int off = 8; off < 32; off <<= 1) {
#pragma unroll
            for (int i = 0; i < 8; ++i) a[i] += __shfl_xor(a[i], off);
        }

        if (r == 0) {
            const float inv = 1.0f / (float)max(cn, 1);
            uint4 su = *(const uint4*)&Tself[(size_t)v * 64 + c * 8];
            float4 bA = *(const float4*)&bias[c * 8];
            float4 bB = *(const float4*)&bias[c * 8 + 4];
            float o[8];
            o[0] = bflo(su.x) + a[0] * inv + bA.x;
            o[1] = bfhi(su.x) + a[1] * inv + bA.y;
            o[2] = bflo(su.y) + a[2] * inv + bA.z;
            o[3] = bfhi(su.y) + a[3] * inv + bA.w;
            o[4] = bflo(su.z) + a[4] * inv + bB.x;
            o[5] = bfhi(su.z) + a[5] * inv + bB.y;
            o[6] = bflo(su.w) + a[6] * inv + bB.z;
            o[7] = bfhi(su.w) + a[7] * inv + bB.w;
#pragma unroll
            for (int i = 0; i < 8; ++i) o[i] = fmaxf(o[i], 0.f);
            uint4 p;
            p.x = pack_bf(o[0], o[1]); p.y = pack_bf(o[2], o[3]);
            p.z = pack_bf(o[4], o[5]); p.w = pack_bf(o[6], o[7]);
            *(uint4*)&h_lds[dloc * HST + c * 8] = p;     // h row -> LDS (not global)
        }
    }
#undef ACC8
    __syncthreads();

    // ---- layer-2 MFMA GEMM on LDS h: wave wv owns rows wv*16..wv*16+15 ----
    // Rows >= 200 read scratch LDS (garbage); their writes are guarded.
    const int lr  = lane & 15;
    const int lk2 = (lane >> 4) << 3;      // 0,8,16,24

    // B fragments (hi/lo split): n = nt*16 + lr, k = ks*32 + lk2 + j
    bf16x8 bhi[4][2], blo[4][2];
#pragma unroll
    for (int nt = 0; nt < 4; ++nt) {
        const int n = nt * 16 + lr;        // 0..63
        const float* Bp = (n < 32) ? (Ws2 + n) : (Wn2 + (n - 32));
#pragma unroll
        for (int ks = 0; ks < 2; ++ks) {
#pragma unroll
            for (int j = 0; j < 8; ++j) {
                float bv = Bp[(size_t)(ks * 32 + lk2 + j) * 32];
                short h, lo;
                split_bf(bv, h, lo);
                bhi[nt][ks][j] = h;
                blo[nt][ks][j] = lo;
            }
        }
    }

    f32x4 acc2[4];
#pragma unroll
    for (int nt = 0; nt < 4; ++nt) {
        f32x4 z = {0.f, 0.f, 0.f, 0.f};
        acc2[nt] = z;
    }
#pragma unroll
    for (int ks = 0; ks < 2; ++ks) {
        const bf16x8 a = *(const bf16x8*)&h_lds[(wv * 16 + lr) * HST + ks * 32 + lk2];
#pragma unroll
        for (int nt = 0; nt < 4; ++nt) {
            acc2[nt] = __builtin_amdgcn_mfma_f32_16x16x32_bf16(a, bhi[nt][ks], acc2[nt], 0, 0, 0);
            acc2[nt] = __builtin_amdgcn_mfma_f32_16x16x32_bf16(a, blo[nt][ks], acc2[nt], 0, 0, 0);
        }
    }

    // store: col n = nt*16+lr; local rows wv*16 + (lane>>4)*4 + rr (guard < BW)
    const int lbase = wv * 16 + ((lane >> 4) << 2);
#pragma unroll
    for (int nt = 0; nt < 4; ++nt) {
        const int n = nt * 16 + lr;
        ushort_t* T = (n < 32) ? (Tself2 + n) : (Tn2 + (n - 32));
#pragma unroll
        for (int rr = 0; rr < 4; ++rr) {
            const int lrow = lbase + rr;
            if (lrow < BW) T[(size_t)(node0 + lrow) * 32] = f2bf(acc2[nt][rr]);
        }
    }
}

// ---------------- Layer-2 gather (F=32): 4 nodes/wave, 16 lanes each ----------------
__global__ __launch_bounds__(256)
void gather2(const ushort_t* __restrict__ Tself,
             const ushort_t* __restrict__ Tn,
             const int* __restrict__ row_ptr,
             const int* __restrict__ csr_src, const float* __restrict__ bias,
             float* __restrict__ out) {
    constexpr int F = 32;
    constexpr int LPR = 4;           // lanes per row (4 x 16B = 64B row)
    constexpr int G = 4;             // row-groups per node (16/LPR)
    constexpr int MAXJ = 8;          // fast-path rows per group (covers cnt<=32)
    const int lane = threadIdx.x & 63;
    const int q  = lane >> 4;        // node slot within wave (0..3)
    const int hl = lane & 15;
    const int r = hl >> 2;           // row-group 0..3
    const int c = hl & 3;            // cols c*8 .. c*8+7
    const int v = (((int)blockIdx.x * (int)blockDim.x + (int)threadIdx.x) >> 6) * 4 + q;
    if (v >= N_NODES) return;
    const int start = row_ptr[v];
    const int cnt   = row_ptr[v + 1] - start;

    float a[8];
#pragma unroll
    for (int i = 0; i < 8; ++i) a[i] = 0.f;

#define ACC8(u)                                           \
    a[0] += bflo(u.x); a[1] += bfhi(u.x);                 \
    a[2] += bflo(u.y); a[3] += bfhi(u.y);                 \
    a[4] += bflo(u.z); a[5] += bfhi(u.z);                 \
    a[6] += bflo(u.w); a[7] += bfhi(u.w);

    // ---- two coalesced index loads per lane: covers indices 0..31 ----
    int idx0 = 0, idx1 = 0;
    if (hl < cnt)      idx0 = csr_src[start + hl];
    if (16 + hl < cnt) idx1 = csr_src[start + 16 + hl];

    const int nfast = (cnt < 32) ? cnt : 32;
    int  sidx[MAXJ];
    bool act[MAXJ];
#pragma unroll
    for (int j = 0; j < MAXJ; ++j) {
        const int t = r + j * G;                 // j<4 -> t<16 ; j>=4 -> t>=16
        act[j] = (t < nfast);
        sidx[j] = (j < 4) ? __shfl(idx0, q * 16 + t)
                          : __shfl(idx1, q * 16 + (t - 16));
    }
    uint4 u[MAXJ];
#pragma unroll
    for (int j = 0; j < MAXJ; ++j) {
        u[j] = make_uint4(0u, 0u, 0u, 0u);
        if (act[j]) u[j] = *(const uint4*)&Tn[(size_t)sidx[j] * F + c * 8];
    }
#pragma unroll
    for (int j = 0; j < MAXJ; ++j) { ACC8(u[j]) }

    // ---- rare tail: cnt > 32 ----
    for (int t = 32 + r; t < cnt; t += G) {
        const int s = csr_src[start + t];
        uint4 uu = *(const uint4*)&Tn[(size_t)s * F + c * 8];
        ACC8(uu)
    }
#undef ACC8

    // ---- reduce across 4 row-groups (within the 16-lane quarter) ----
#pragma unroll
    for (int off = LPR; off < 16; off <<= 1) {
#pragma unroll
        for (int i = 0; i < 8; ++i) a[i] += __shfl_xor(a[i], off);
    }

    if (r == 0) {
        const float inv = 1.0f / (float)max(cnt, 1);
        uint4 su = *(const uint4*)&Tself[(size_t)v * F + c * 8];
        float4 bA = *(const float4*)&bias[c * 8];
        float4 bB = *(const float4*)&bias[c * 8 + 4];
        float o[8];
        o[0] = bflo(su.x) + a[0] * inv + bA.x;
        o[1] = bfhi(su.x) + a[1] * inv + bA.y;
        o[2] = bflo(su.y) + a[2] * inv + bA.z;
        o[3] = bfhi(su.y) + a[3] * inv + bA.w;
        o[4] = bflo(su.z) + a[4] * inv + bB.x;
        o[5] = bfhi(su.z) + a[5] * inv + bB.y;
        o[6] = bflo(su.w) + a[6] * inv + bB.z;
        o[7] = bfhi(su.w) + a[7] * inv + bB.w;
        *(float4*)&out[(size_t)v * F + c * 8]     = make_float4(o[0], o[1], o[2], o[3]);
        *(float4*)&out[(size_t)v * F + c * 8 + 4] = make_float4(o[4], o[5], o[6], o[7]);
    }
}

extern "C" void kernel_launch(void* const* d_in, const int* in_sizes, int n_in,
                              void* d_out, int out_size, void* d_ws, size_t ws_size,
                              hipStream_t stream) {
    const float* features = (const float*)d_in[0];
    const float* W_self1  = (const float*)d_in[1];
    const float* W_neigh1 = (const float*)d_in[2];
    const float* b1       = (const float*)d_in[3];
    const float* W_self2  = (const float*)d_in[4];
    const float* W_neigh2 = (const float*)d_in[5];
    const float* b2       = (const float*)d_in[6];
    const int*   src      = (const int*)d_in[7];
    const int*   dst      = (const int*)d_in[8];

    // Workspace:
    //   Tself1 : N*64 bf16 (6.4 MB)
    //   Tn1    : N*64 bf16 (6.4 MB)
    //   T2     : N*64 bf16 (6.4 MB) = Tself2 (N*32) | Tn2 (N*32)
    //   row_ptr: N+1; csr_src: E; brec: E; blocktot: NB*PBLOCKS
    ushort_t* Tself1 = (ushort_t*)d_ws;
    ushort_t* Tn1    = Tself1 + (size_t)N_NODES * 64;
    ushort_t* T2     = Tn1 + (size_t)N_NODES * 64;
    int* row_ptr     = (int*)(T2 + (size_t)N_NODES * 64);
    int* csr_src     = row_ptr + (N_NODES + 1);
    unsigned int* brec = (unsigned int*)(csr_src + N_EDGES);
    int* blocktot    = (int*)(brec + N_EDGES);

    ushort_t* Tself2 = T2;
    ushort_t* Tn2    = T2 + (size_t)N_NODES * 32;

    // ---- 1: layer-1 MFMA GEMM overlapped with CSR count ----
    gemm128_and_count<<<GEMM_BLOCKS + PBLOCKS, 256, 0, stream>>>(
        features, W_self1, W_neigh1, Tself1, Tn1, dst, blocktot);
    // ---- 2: radix partition write ----
    part_write<<<PBLOCKS, 256, 0, stream>>>(src, dst, blocktot, brec);
    // ---- 3: FUSED CSR build + layer-1 gather + layer-2 GEMM (250 blocks) ----
    csr_gather1_g2<<<NB, 1024, 0, stream>>>(
        blocktot, brec, csr_src, row_ptr, Tself1, Tn1, b1,
        W_self2, W_neigh2, Tself2, Tn2);
    // ---- 4: layer-2 gather + epilogue -> out (fp32) ----
    gather2<<<(N_NODES + 15) / 16, 256, 0, stream>>>(
        Tself2, Tn2, row_ptr, csr_src, b2, (float*)d_out);
}

// Round 12
// 155.012 us; speedup vs baseline: 1.1844x; 1.0174x over previous
//
#include <hip/hip_runtime.h>

#define N_NODES 50000
#define N_EDGES 800000
#define NB 250                 // buckets of 200 nodes: 250*200 == 50000 exactly
#define BW 200                 // bucket width (nodes)
#define PBLOCKS 256            // partition blocks (== count chunks)
#define CHUNK 3125             // N_EDGES / PBLOCKS (exact)
#define GEMM_BLOCKS 782        // ceil(50000/64)
#define CSR_CAP 4096           // LDS csr capacity per bucket (mean 3200 + 15 sigma)
#define HST 80                 // h_lds row stride in bf16 (160 B -> 8-bank skew)

typedef unsigned short ushort_t;
typedef __attribute__((ext_vector_type(8))) short bf16x8;   // 8 bf16 = 4 VGPR
typedef __attribute__((ext_vector_type(4))) float f32x4;    // MFMA 16x16 accum

// LESSON (round 5): LDS scatter-accumulate via __hip_atomic_fetch_add was
// catastrophically slow (350us, VALUBusy 1%). Keep the CSR + batched point-load
// gather structure below; it is the verified-good shape.
// LESSON (round 3): per-lane global weight loads + shfl GEMM fusion gets sunk
// by the compiler into a serial latency chain. Fuse GEMMs via LDS + MFMA only.
// LESSON (rounds 8-11): fused kernel wants ONE 16-wave block per CU; 250
// buckets of 200 nodes covers all CUs with no tail (157.7us best).
// ROUND 12: reschedule the dependency graph -- gemm1 is independent of the
// CSR chain, so co-launch part_write WITH gemm1 (hides ~15us) and expose only
// the cheap part_count (~3us).

__device__ __forceinline__ float bflo(unsigned int u) {
    return __uint_as_float(u << 16);
}
__device__ __forceinline__ float bfhi(unsigned int u) {
    return __uint_as_float(u & 0xffff0000u);
}
__device__ __forceinline__ ushort_t f2bf(float f) {   // round-to-nearest-even
    unsigned int x = __float_as_uint(f);
    return (ushort_t)((x + 0x7fffu + ((x >> 16) & 1u)) >> 16);
}
__device__ __forceinline__ unsigned int pack_bf(float lo, float hi) {
    return (unsigned int)f2bf(lo) | ((unsigned int)f2bf(hi) << 16);
}
// split fp32 into bf16 hi + bf16 lo (residual); hi+lo reproduces v to ~2^-17 rel
__device__ __forceinline__ void split_bf(float v, short& hi, short& lo) {
    ushort_t h = f2bf(v);
    float r = v - __uint_as_float((unsigned int)h << 16);
    hi = (short)h;
    lo = (short)f2bf(r);
}
// bucket(d) = d / 200 for d < 50000, via d/200 = (d>>3)/25 and magic-div by 25:
// m = ceil(2^17/25) = 5243, err = 3; 3 * 6249 < 2^17 -> exact (Granlund).
__device__ __forceinline__ int bucket_of(int d) {
    return ((d >> 3) * 5243) >> 17;
}

// ---------------- part_count: standalone (exposed, ~3us) ----------------
__global__ __launch_bounds__(1024)
void part_count(const int* __restrict__ dst, int* __restrict__ blocktot) {
    __shared__ int hist[NB];
    const int pb = blockIdx.x;
    for (int i = threadIdx.x; i < NB; i += 1024) hist[i] = 0;
    __syncthreads();
    const int e0 = pb * CHUNK;
    const int e1 = e0 + CHUNK;
    for (int e = e0 + (int)threadIdx.x; e < e1; e += 1024)
        atomicAdd(&hist[bucket_of(dst[e])], 1);
    __syncthreads();
    for (int i = threadIdx.x; i < NB; i += 1024)
        blocktot[i * PBLOCKS + pb] = hist[i];
}

// ---------------- Co-launched: part_write (blocks 0..255) + layer-1 GEMM ----
// part_write depends only on blocktot (kernel 1); the GEMM is independent of
// the CSR chain -> they overlap inside one launch. part_write blocks first so
// they dispatch early.
__global__ __launch_bounds__(256)
void gemm_and_write(const float* __restrict__ A,
                    const float* __restrict__ B1,   // [64,64] Ws1
                    const float* __restrict__ B2,   // [64,64] Wn1
                    ushort_t* __restrict__ Cself,   // [N,64] bf16
                    ushort_t* __restrict__ Cn,      // [N,64] bf16
                    const int* __restrict__ src,
                    const int* __restrict__ dst,
                    const int* __restrict__ blocktot,
                    unsigned int* __restrict__ brec) {
    if (blockIdx.x < PBLOCKS) {
        // ---- part_write with self-computed prefixes ----
        __shared__ int ssum[256];
        __shared__ int cur[NB];
        const int pb = blockIdx.x;           // 0..PBLOCKS-1
        const int t  = threadIdx.x;

        int rsum = 0, mypart = 0;
        if (t < NB) {
            const int* rp = blocktot + t * PBLOCKS;
#pragma unroll 8
            for (int j = 0; j < PBLOCKS; ++j) {
                if (j == pb) mypart = rsum;
                rsum += rp[j];
            }
        }
        ssum[t] = (t < NB) ? rsum : 0;
        __syncthreads();
        for (int off = 1; off < 256; off <<= 1) {
            int add = (t >= off) ? ssum[t - off] : 0;
            __syncthreads();
            ssum[t] += add;
            __syncthreads();
        }
        if (t < NB) cur[t] = (ssum[t] - rsum) + mypart;   // rowpre + colpart
        __syncthreads();

        const int e0 = pb * CHUNK;
        const int e1 = e0 + CHUNK;
        for (int e = e0 + t; e < e1; e += 256) {
            int d = dst[e];
            int s = src[e];
            int b = bucket_of(d);
            int pos = atomicAdd(&cur[b], 1);
            brec[pos] = ((unsigned int)(d - b * BW) << 16) | (unsigned int)s;
        }
        return;
    }

    // ---- layer-1 MFMA GEMM tile ----
    const int l  = threadIdx.x & 63;
    const int w  = threadIdx.x >> 6;     // wave 0..3
    const int lr = l & 15;
    const int lk = (l >> 4) << 3;        // 0,8,16,24

    // ---- B fragments in registers (hi/lo split), cols 32w .. 32w+31 ----
    bf16x8 bhi[2][2], blo[2][2];         // [nt][ks]
#pragma unroll
    for (int nt = 0; nt < 2; ++nt) {
        const int n = w * 32 + nt * 16 + lr;             // 0..127
        const float* Bp = (n < 64) ? (B1 + n) : (B2 + (n - 64));
#pragma unroll
        for (int ks = 0; ks < 2; ++ks) {
#pragma unroll
            for (int j = 0; j < 8; ++j) {
                float bv = Bp[(size_t)(ks * 32 + lk + j) * 64];
                short h, lo;
                split_bf(bv, h, lo);
                bhi[nt][ks][j] = h;
                blo[nt][ks][j] = lo;
            }
        }
    }

    const int m0 = (blockIdx.x - PBLOCKS) * 64;
    f32x4 acc[4][2];
#pragma unroll
    for (int mt = 0; mt < 4; ++mt)
#pragma unroll
        for (int nt = 0; nt < 2; ++nt) {
            f32x4 z = {0.f, 0.f, 0.f, 0.f};
            acc[mt][nt] = z;
        }

#pragma unroll
    for (int mt = 0; mt < 4; ++mt) {
        const int m = m0 + mt * 16 + lr;
        const bool valid = (m < N_NODES);
        const float* Ap = A + (size_t)m * 64 + lk;
#pragma unroll
        for (int ks = 0; ks < 2; ++ks) {
            float4 f0, f1;
            if (valid) {
                f0 = *(const float4*)(Ap + ks * 32);
                f1 = *(const float4*)(Ap + ks * 32 + 4);
            } else {
                f0 = make_float4(0.f, 0.f, 0.f, 0.f);
                f1 = f0;
            }
            const float fv[8] = {f0.x, f0.y, f0.z, f0.w, f1.x, f1.y, f1.z, f1.w};
            bf16x8 ahi, alo;
#pragma unroll
            for (int j = 0; j < 8; ++j) {
                short h, lo;
                split_bf(fv[j], h, lo);
                ahi[j] = h;
                alo[j] = lo;
            }
#pragma unroll
            for (int nt = 0; nt < 2; ++nt) {
                acc[mt][nt] = __builtin_amdgcn_mfma_f32_16x16x32_bf16(
                    ahi, bhi[nt][ks], acc[mt][nt], 0, 0, 0);
                acc[mt][nt] = __builtin_amdgcn_mfma_f32_16x16x32_bf16(
                    alo, bhi[nt][ks], acc[mt][nt], 0, 0, 0);
                acc[mt][nt] = __builtin_amdgcn_mfma_f32_16x16x32_bf16(
                    ahi, blo[nt][ks], acc[mt][nt], 0, 0, 0);
            }
        }
    }

    // ---- store: D lane col = l&15 (+tiles), rows (l>>4)*4 + r ----
#pragma unroll
    for (int mt = 0; mt < 4; ++mt) {
        const int mbase = m0 + mt * 16 + ((l >> 4) << 2);
#pragma unroll
        for (int nt = 0; nt < 2; ++nt) {
            const int n = w * 32 + nt * 16 + lr;
            ushort_t* T = (n < 64) ? (Cself + n) : (Cn + (n - 64));
#pragma unroll
            for (int r = 0; r < 4; ++r) {
                const int m = mbase + r;
                if (m < N_NODES) T[(size_t)m * 64] = f2bf(acc[mt][nt][r]);
            }
        }
    }
}

// ---------------- FUSED: bucket CSR build + layer-1 gather + layer-2 MFMA GEMM ----
// One 1024-thread (16-wave) block per 200-node bucket. 250 blocks -> every CU
// busy, zero tail. Phases: bucket scan -> histogram -> node scan -> scatter ->
// gather (verified round-4 inner shape) -> layer-2 MFMA GEMM on LDS h.
__global__ __launch_bounds__(1024)
void csr_gather1_g2(const int* __restrict__ blocktot,
                    const unsigned int* __restrict__ brec,
                    int* __restrict__ csr_src, int* __restrict__ row_ptr,
                    const ushort_t* __restrict__ Tself,
                    const ushort_t* __restrict__ Tn,
                    const float* __restrict__ bias,        // b1
                    const float* __restrict__ Ws2,         // [64,32]
                    const float* __restrict__ Wn2,         // [64,32]
                    ushort_t* __restrict__ Tself2,         // [N,32] bf16
                    ushort_t* __restrict__ Tn2) {          // [N,32] bf16
    __shared__ int ssum[256];
    __shared__ int cnt[256];
    __shared__ int rs[256];
    __shared__ int cur[256];
    __shared__ int csr_lds[CSR_CAP];        // 16 KB
    __shared__ ushort_t h_lds[256 * HST];   // 40 KB (rows 200..255 scratch)

    const int b = blockIdx.x;
    const int node0 = b * BW;
    const int t = threadIdx.x;

    // ---- bucket [w0,w1) from blocktot row sums + 256-scan ----
    if (t < 256) {
        int rsum = 0;
        if (t < NB) {
            const int* rp = blocktot + t * PBLOCKS;
#pragma unroll 8
            for (int j = 0; j < PBLOCKS; ++j) rsum += rp[j];
        }
        ssum[t] = rsum;
        cnt[t] = 0;
    }
    __syncthreads();
    for (int off = 1; off < 256; off <<= 1) {
        int add = (t < 256 && t >= off) ? ssum[t - off] : 0;
        __syncthreads();
        if (t < 256) ssum[t] += add;
        __syncthreads();
    }
    const int w0 = (b == 0) ? 0 : ssum[b - 1];
    const int w1 = ssum[b];
    __syncthreads();

    // ---- histogram of own ~3200 records ----
    for (int i = w0 + t; i < w1; i += 1024)
        atomicAdd(&cnt[brec[i] >> 16], 1);
    __syncthreads();

    // ---- scan cnt -> rs (exclusive, bucket-local); row_ptr global ----
    if (t < 256) cur[t] = cnt[t];
    __syncthreads();
    for (int off = 1; off < 256; off <<= 1) {
        int add = (t < 256 && t >= off) ? cur[t - off] : 0;
        __syncthreads();
        if (t < 256) cur[t] += add;
        __syncthreads();
    }
    if (t < 256) {
        const int excl = cur[t] - cnt[t];
        rs[t] = excl;
        if (t < BW) row_ptr[node0 + t] = w0 + excl;
        cur[t] = excl;                      // scatter cursor (bucket-local)
    }
    if (b == NB - 1 && t == 0) row_ptr[N_NODES] = N_EDGES;
    __syncthreads();

    // ---- scatter: LDS csr + global csr_src (for gather2) ----
    for (int i = w0 + t; i < w1; i += 1024) {
        const unsigned int r = brec[i];
        const int pos = atomicAdd(&cur[r >> 16], 1);
        const int s = (int)(r & 0xffffu);
        csr_src[w0 + pos] = s;
        if (pos < CSR_CAP) csr_lds[pos] = s;
    }
    __syncthreads();

    // ---- gather phase: 16 waves x 7 iters x 2 nodes -> 200 nodes ----
    const int wv   = t >> 6;           // wave 0..15
    const int lane = t & 63;
    const int half = lane >> 5;        // node slot within wave
    const int hl   = lane & 31;
    const int r = hl >> 3;             // row-group 0..3
    const int c = hl & 7;              // cols c*8 .. c*8+7

#define ACC8(u)                                           \
    a[0] += bflo(u.x); a[1] += bfhi(u.x);                 \
    a[2] += bflo(u.y); a[3] += bfhi(u.y);                 \
    a[4] += bflo(u.z); a[5] += bfhi(u.z);                 \
    a[6] += bflo(u.w); a[7] += bfhi(u.w);

    for (int it = 0; it < 7; ++it) {
        const int pair = wv + (it << 4);        // 0..111
        if (pair >= 100) continue;              // 100 pairs = 200 nodes
        const int dloc = (pair << 1) + half;    // 0..199
        const int v = node0 + dloc;             // always < N_NODES (250*200 exact)
        const int sl = rs[dloc];
        const int cn = cnt[dloc];

        float a[8];
#pragma unroll
        for (int i = 0; i < 8; ++i) a[i] = 0.f;

        const int nfast = (cn < 32) ? cn : 32;
        int  sidx[8];
        bool act[8];
#pragma unroll
        for (int j = 0; j < 8; ++j) {
            const int tt = r + (j << 2);
            act[j] = (tt < nfast);
            sidx[j] = 0;
            if (act[j]) {
                const int ad = sl + tt;
                sidx[j] = (ad < CSR_CAP) ? csr_lds[ad] : csr_src[w0 + ad];
            }
        }
        uint4 u[8];
#pragma unroll
        for (int j = 0; j < 8; ++j) {
            u[j] = make_uint4(0u, 0u, 0u, 0u);
            if (act[j]) u[j] = *(const uint4*)&Tn[(size_t)sidx[j] * 64 + c * 8];
        }
#pragma unroll
        for (int j = 0; j < 8; ++j) { ACC8(u[j]) }

        // rare tail: cn > 32
        for (int tt = 32 + r; tt < cn; tt += 4) {
            const int ad = sl + tt;
            const int s = (ad < CSR_CAP) ? csr_lds[ad] : csr_src[w0 + ad];
            const uint4 uu = *(const uint4*)&Tn[(size_t)s * 64 + c * 8];
            ACC8(uu)
        }

        // butterfly within the 32-lane half
#pragma unroll
        for (int off = 8; off < 32; off <<= 1) {
#pragma unroll
            for (int i = 0; i < 8; ++i) a[i] += __shfl_xor(a[i], off);
        }

        if (r == 0) {
            const float inv = 1.0f / (float)max(cn, 1);
            uint4 su = *(const uint4*)&Tself[(size_t)v * 64 + c * 8];
            float4 bA = *(const float4*)&bias[c * 8];
            float4 bB = *(const float4*)&bias[c * 8 + 4];
            float o[8];
            o[0] = bflo(su.x) + a[0] * inv + bA.x;
            o[1] = bfhi(su.x) + a[1] * inv + bA.y;
            o[2] = bflo(su.y) + a[2] * inv + bA.z;
            o[3] = bfhi(su.y) + a[3] * inv + bA.w;
            o[4] = bflo(su.z) + a[4] * inv + bB.x;
            o[5] = bfhi(su.z) + a[5] * inv + bB.y;
            o[6] = bflo(su.w) + a[6] * inv + bB.z;
            o[7] = bfhi(su.w) + a[7] * inv + bB.w;
#pragma unroll
            for (int i = 0; i < 8; ++i) o[i] = fmaxf(o[i], 0.f);
            uint4 p;
            p.x = pack_bf(o[0], o[1]); p.y = pack_bf(o[2], o[3]);
            p.z = pack_bf(o[4], o[5]); p.w = pack_bf(o[6], o[7]);
            *(uint4*)&h_lds[dloc * HST + c * 8] = p;     // h row -> LDS (not global)
        }
    }
#undef ACC8
    __syncthreads();

    // ---- layer-2 MFMA GEMM on LDS h: wave wv owns rows wv*16..wv*16+15 ----
    // Rows >= 200 read scratch LDS (garbage); their writes are guarded.
    const int lr  = lane & 15;
    const int lk2 = (lane >> 4) << 3;      // 0,8,16,24

    // B fragments (hi/lo split): n = nt*16 + lr, k = ks*32 + lk2 + j
    bf16x8 bhi[4][2], blo[4][2];
#pragma unroll
    for (int nt = 0; nt < 4; ++nt) {
        const int n = nt * 16 + lr;        // 0..63
        const float* Bp = (n < 32) ? (Ws2 + n) : (Wn2 + (n - 32));
#pragma unroll
        for (int ks = 0; ks < 2; ++ks) {
#pragma unroll
            for (int j = 0; j < 8; ++j) {
                float bv = Bp[(size_t)(ks * 32 + lk2 + j) * 32];
                short h, lo;
                split_bf(bv, h, lo);
                bhi[nt][ks][j] = h;
                blo[nt][ks][j] = lo;
            }
        }
    }

    f32x4 acc2[4];
#pragma unroll
    for (int nt = 0; nt < 4; ++nt) {
        f32x4 z = {0.f, 0.f, 0.f, 0.f};
        acc2[nt] = z;
    }
#pragma unroll
    for (int ks = 0; ks < 2; ++ks) {
        const bf16x8 a = *(const bf16x8*)&h_lds[(wv * 16 + lr) * HST + ks * 32 + lk2];
#pragma unroll
        for (int nt = 0; nt < 4; ++nt) {
            acc2[nt] = __builtin_amdgcn_mfma_f32_16x16x32_bf16(a, bhi[nt][ks], acc2[nt], 0, 0, 0);
            acc2[nt] = __builtin_amdgcn_mfma_f32_16x16x32_bf16(a, blo[nt][ks], acc2[nt], 0, 0, 0);
        }
    }

    // store: col n = nt*16+lr; local rows wv*16 + (lane>>4)*4 + rr (guard < BW)
    const int lbase = wv * 16 + ((lane >> 4) << 2);
#pragma unroll
    for (int nt = 0; nt < 4; ++nt) {
        const int n = nt * 16 + lr;
        ushort_t* T = (n < 32) ? (Tself2 + n) : (Tn2 + (n - 32));
#pragma unroll
        for (int rr = 0; rr < 4; ++rr) {
            const int lrow = lbase + rr;
            if (lrow < BW) T[(size_t)(node0 + lrow) * 32] = f2bf(acc2[nt][rr]);
        }
    }
}

// ---------------- Layer-2 gather (F=32): 4 nodes/wave, 16 lanes each ----------------
__global__ __launch_bounds__(256)
void gather2(const ushort_t* __restrict__ Tself,
             const ushort_t* __restrict__ Tn,
             const int* __restrict__ row_ptr,
             const int* __restrict__ csr_src, const float* __restrict__ bias,
             float* __restrict__ out) {
    constexpr int F = 32;
    constexpr int LPR = 4;           // lanes per row (4 x 16B = 64B row)
    constexpr int G = 4;             // row-groups per node (16/LPR)
    constexpr int MAXJ = 8;          // fast-path rows per group (covers cnt<=32)
    const int lane = threadIdx.x & 63;
    const int q  = lane >> 4;        // node slot within wave (0..3)
    const int hl = lane & 15;
    const int r = hl >> 2;           // row-group 0..3
    const int c = hl & 3;            // cols c*8 .. c*8+7
    const int v = (((int)blockIdx.x * (int)blockDim.x + (int)threadIdx.x) >> 6) * 4 + q;
    if (v >= N_NODES) return;
    const int start = row_ptr[v];
    const int cnt   = row_ptr[v + 1] - start;

    float a[8];
#pragma unroll
    for (int i = 0; i < 8; ++i) a[i] = 0.f;

#define ACC8(u)                                           \
    a[0] += bflo(u.x); a[1] += bfhi(u.x);                 \
    a[2] += bflo(u.y); a[3] += bfhi(u.y);                 \
    a[4] += bflo(u.z); a[5] += bfhi(u.z);                 \
    a[6] += bflo(u.w); a[7] += bfhi(u.w);

    // ---- two coalesced index loads per lane: covers indices 0..31 ----
    int idx0 = 0, idx1 = 0;
    if (hl < cnt)      idx0 = csr_src[start + hl];
    if (16 + hl < cnt) idx1 = csr_src[start + 16 + hl];

    const int nfast = (cnt < 32) ? cnt : 32;
    int  sidx[MAXJ];
    bool act[MAXJ];
#pragma unroll
    for (int j = 0; j < MAXJ; ++j) {
        const int t = r + j * G;                 // j<4 -> t<16 ; j>=4 -> t>=16
        act[j] = (t < nfast);
        sidx[j] = (j < 4) ? __shfl(idx0, q * 16 + t)
                          : __shfl(idx1, q * 16 + (t - 16));
    }
    uint4 u[MAXJ];
#pragma unroll
    for (int j = 0; j < MAXJ; ++j) {
        u[j] = make_uint4(0u, 0u, 0u, 0u);
        if (act[j]) u[j] = *(const uint4*)&Tn[(size_t)sidx[j] * F + c * 8];
    }
#pragma unroll
    for (int j = 0; j < MAXJ; ++j) { ACC8(u[j]) }

    // ---- rare tail: cnt > 32 ----
    for (int t = 32 + r; t < cnt; t += G) {
        const int s = csr_src[start + t];
        uint4 uu = *(const uint4*)&Tn[(size_t)s * F + c * 8];
        ACC8(uu)
    }
#undef ACC8

    // ---- reduce across 4 row-groups (within the 16-lane quarter) ----
#pragma unroll
    for (int off = LPR; off < 16; off <<= 1) {
#pragma unroll
        for (int i = 0; i < 8; ++i) a[i] += __shfl_xor(a[i], off);
    }

    if (r == 0) {
        const float inv = 1.0f / (float)max(cnt, 1);
        uint4 su = *(const uint4*)&Tself[(size_t)v * F + c * 8];
        float4 bA = *(const float4*)&bias[c * 8];
        float4 bB = *(const float4*)&bias[c * 8 + 4];
        float o[8];
        o[0] = bflo(su.x) + a[0] * inv + bA.x;
        o[1] = bfhi(su.x) + a[1] * inv + bA.y;
        o[2] = bflo(su.y) + a[2] * inv + bA.z;
        o[3] = bfhi(su.y) + a[3] * inv + bA.w;
        o[4] = bflo(su.z) + a[4] * inv + bB.x;
        o[5] = bfhi(su.z) + a[5] * inv + bB.y;
        o[6] = bflo(su.w) + a[6] * inv + bB.z;
        o[7] = bfhi(su.w) + a[7] * inv + bB.w;
        *(float4*)&out[(size_t)v * F + c * 8]     = make_float4(o[0], o[1], o[2], o[3]);
        *(float4*)&out[(size_t)v * F + c * 8 + 4] = make_float4(o[4], o[5], o[6], o[7]);
    }
}

extern "C" void kernel_launch(void* const* d_in, const int* in_sizes, int n_in,
                              void* d_out, int out_size, void* d_ws, size_t ws_size,
                              hipStream_t stream) {
    const float* features = (const float*)d_in[0];
    const float* W_self1  = (const float*)d_in[1];
    const float* W_neigh1 = (const float*)d_in[2];
    const float* b1       = (const float*)d_in[3];
    const float* W_self2  = (const float*)d_in[4];
    const float* W_neigh2 = (const float*)d_in[5];
    const float* b2       = (const float*)d_in[6];
    const int*   src      = (const int*)d_in[7];
    const int*   dst      = (const int*)d_in[8];

    // Workspace:
    //   Tself1 : N*64 bf16 (6.4 MB)
    //   Tn1    : N*64 bf16 (6.4 MB)
    //   T2     : N*64 bf16 (6.4 MB) = Tself2 (N*32) | Tn2 (N*32)
    //   row_ptr: N+1; csr_src: E; brec: E; blocktot: NB*PBLOCKS
    ushort_t* Tself1 = (ushort_t*)d_ws;
    ushort_t* Tn1    = Tself1 + (size_t)N_NODES * 64;
    ushort_t* T2     = Tn1 + (size_t)N_NODES * 64;
    int* row_ptr     = (int*)(T2 + (size_t)N_NODES * 64);
    int* csr_src     = row_ptr + (N_NODES + 1);
    unsigned int* brec = (unsigned int*)(csr_src + N_EDGES);
    int* blocktot    = (int*)(brec + N_EDGES);

    ushort_t* Tself2 = T2;
    ushort_t* Tn2    = T2 + (size_t)N_NODES * 32;

    // ---- 1: bucket count (exposed, cheap) ----
    part_count<<<PBLOCKS, 1024, 0, stream>>>(dst, blocktot);
    // ---- 2: part_write co-launched with layer-1 MFMA GEMM (independent) ----
    gemm_and_write<<<PBLOCKS + GEMM_BLOCKS, 256, 0, stream>>>(
        features, W_self1, W_neigh1, Tself1, Tn1, src, dst, blocktot, brec);
    // ---- 3: FUSED CSR build + layer-1 gather + layer-2 GEMM (250 blocks) ----
    csr_gather1_g2<<<NB, 1024, 0, stream>>>(
        blocktot, brec, csr_src, row_ptr, Tself1, Tn1, b1,
        W_self2, W_neigh2, Tself2, Tn2);
    // ---- 4: layer-2 gather + epilogue -> out (fp32) ----
    gather2<<<(N_NODES + 15) / 16, 256, 0, stream>>>(
        Tself2, Tn2, row_ptr, csr_src, b2, (float*)d_out);
}